// Round 11
// baseline (436.353 us; speedup 1.0000x reference)
//
#include <hip/hip_runtime.h>
#include <stdint.h>

// ---------------- problem constants ----------------
#define B_BATCH 16
#define SEQ     2048
#define DIMD    128
#define QT_OUT  14            // output rows per tile
#define SROWS   16            // score rows in LDS (halo +1 each side)
#define SCALE   0.08838834764831845f   // 1/sqrt(128)
#define L2E     1.4426950408889634f

#define SC_STRIDE 4096                 // bytes per score row (2048 bf16)
#define LDS_TOTAL (SROWS * SC_STRIDE)  // 65536 -> 2 blocks/CU (if VGPR <= 128)

typedef __attribute__((ext_vector_type(8))) short bf16x8;
typedef __attribute__((ext_vector_type(4))) float f32x4;

__device__ __forceinline__ unsigned short f2bf(float f) {
  union { float f; uint32_t u; } v; v.f = f;
  uint32_t u = v.u;
  return (unsigned short)((u + 0x7FFFu + ((u >> 16) & 1u)) >> 16);  // RNE
}
__device__ __forceinline__ float bf2f(unsigned short h) {
  union { uint32_t u; float f; } v; v.u = ((uint32_t)h) << 16;
  return v.f;
}

// ---------------- prepass 1: K fp32 -> bf16 (row-major) ----------------
__global__ __launch_bounds__(256) void cvt_bf16(const float* __restrict__ in,
                                                unsigned short* __restrict__ out) {
  const size_t i = (size_t)blockIdx.x * 256 + threadIdx.x;
  const float4 a = *(const float4*)(in + i * 8);
  const float4 b = *(const float4*)(in + i * 8 + 4);
  uint4 o;
  o.x = (uint32_t)f2bf(a.x) | ((uint32_t)f2bf(a.y) << 16);
  o.y = (uint32_t)f2bf(a.z) | ((uint32_t)f2bf(a.w) << 16);
  o.z = (uint32_t)f2bf(b.x) | ((uint32_t)f2bf(b.y) << 16);
  o.w = (uint32_t)f2bf(b.z) | ((uint32_t)f2bf(b.w) << 16);
  *(uint4*)(out + i * 8) = o;
}

// ---------------- prepass 2: V -> V^T bf16 ([b][d][k]) ----------------
__global__ __launch_bounds__(256) void transpose_v(const float* __restrict__ V,
                                                   unsigned short* __restrict__ Vt) {
  __shared__ float tl[64][65];
  const int b  = blockIdx.x >> 6;
  const int kt = (blockIdx.x & 63) >> 1;
  const int dt = blockIdx.x & 1;
  const int k0 = kt * 64, d0 = dt * 64;
  const int tid = threadIdx.x;
  const int r = tid >> 4, c4 = (tid & 15) * 4;
  const float* Vb = V + (size_t)b * SEQ * DIMD;
#pragma unroll
  for (int ii = 0; ii < 4; ++ii) {
    const int row = ii * 16 + r;
    float4 v = *(const float4*)(Vb + (size_t)(k0 + row) * DIMD + d0 + c4);
    tl[row][c4 + 0] = v.x; tl[row][c4 + 1] = v.y;
    tl[row][c4 + 2] = v.z; tl[row][c4 + 3] = v.w;
  }
  __syncthreads();
  unsigned short* VtB = Vt + (size_t)b * DIMD * SEQ;
#pragma unroll
  for (int ii = 0; ii < 4; ++ii) {
    const int drow = ii * 16 + r;
    ushort4 o;
    o.x = f2bf(tl[c4 + 0][drow]); o.y = f2bf(tl[c4 + 1][drow]);
    o.z = f2bf(tl[c4 + 2][drow]); o.w = f2bf(tl[c4 + 3][drow]);
    *(ushort4*)(VtB + (size_t)(d0 + drow) * SEQ + k0 + c4) = o;
  }
}

// ---------------- fused: QK^T -> conv -> softmax -> (PV, atten out) ----------------
// 512 threads (8 waves), 64 KiB LDS. NO register cap: let the compiler allocate
// what phase 2 needs (~110 VGPR) -> no scratch spill (the R3-R10 hidden bottleneck).
__global__ __launch_bounds__(512) void fused_attn(
    const float* __restrict__ Q, const unsigned short* __restrict__ Kb,
    const unsigned short* __restrict__ Vt, const int* __restrict__ msk,
    const float* __restrict__ cw, const float* __restrict__ cbv,
    float* __restrict__ ctx, float* __restrict__ attn) {
  __shared__ __align__(16) char smem[LDS_TOTAL];

  const int bid = blockIdx.x;
  // batch<->XCD affinity: b%8 == bid%8 -> 2 batches per XCD L2
  const int b  = bid & 15;
  const int t  = bid >> 4;
  const int g0 = t * QT_OUT;
  const int tid = threadIdx.x;
  const int w = tid >> 6, lane = tid & 63, l15 = lane & 15, hi = lane >> 4;

  float w9[9];
#pragma unroll
  for (int i = 0; i < 9; ++i) w9[i] = cw[b * 9 + i];
  const float bias = cbv[b];

  // per-lane column mask bits: col = jb*512 + lane*8 + c  ->  bit jb*8+c
  uint32_t mb = 0;
  {
    const int* mp = msk + b * SEQ;
#pragma unroll
    for (int jb = 0; jb < 4; ++jb) {
      int4 a = *(const int4*)(mp + jb * 512 + lane * 8);
      int4 bq = *(const int4*)(mp + jb * 512 + lane * 8 + 4);
      mb |= (a.x  != 0 ? 1u : 0u) << (jb * 8 + 0);
      mb |= (a.y  != 0 ? 1u : 0u) << (jb * 8 + 1);
      mb |= (a.z  != 0 ? 1u : 0u) << (jb * 8 + 2);
      mb |= (a.w  != 0 ? 1u : 0u) << (jb * 8 + 3);
      mb |= (bq.x != 0 ? 1u : 0u) << (jb * 8 + 4);
      mb |= (bq.y != 0 ? 1u : 0u) << (jb * 8 + 5);
      mb |= (bq.z != 0 ? 1u : 0u) << (jb * 8 + 6);
      mb |= (bq.w != 0 ? 1u : 0u) << (jb * 8 + 7);
    }
  }

  // ---- Q fragments (A operand): score row l15 = q-row g0-1+l15 (clamped; gated at conv) ----
  bf16x8 aq[4];
  {
    int grow = g0 - 1 + l15;
    grow = grow < 0 ? 0 : (grow > SEQ - 1 ? SEQ - 1 : grow);
    const float* qp = Q + ((size_t)(b * SEQ + grow)) * DIMD + hi * 8;
#pragma unroll
    for (int ks = 0; ks < 4; ++ks) {
      float4 x = *(const float4*)(qp + ks * 32);
      float4 y = *(const float4*)(qp + ks * 32 + 4);
      bf16x8 f;
      f[0] = (short)f2bf(x.x); f[1] = (short)f2bf(x.y);
      f[2] = (short)f2bf(x.z); f[3] = (short)f2bf(x.w);
      f[4] = (short)f2bf(y.x); f[5] = (short)f2bf(y.y);
      f[6] = (short)f2bf(y.z); f[7] = (short)f2bf(y.w);
      aq[ks] = f;
    }
  }

  // ======= phase 1: QK^T, barrier-free. wave w owns keys [w*256, w*256+256) =======
  {
    const unsigned short* KbB = Kb + (size_t)b * SEQ * DIMD;
    const int k0w = w * 256;
#pragma unroll 4
    for (int kc = 0; kc < 16; ++kc) {
      const int k0 = k0w + kc * 16;
      const unsigned short* kp = KbB + (size_t)(k0 + l15) * DIMD + hi * 8;
      bf16x8 bk0 = *(const bf16x8*)(kp);
      bf16x8 bk1 = *(const bf16x8*)(kp + 32);
      bf16x8 bk2 = *(const bf16x8*)(kp + 64);
      bf16x8 bk3 = *(const bf16x8*)(kp + 96);
      f32x4 acc = {0.f, 0.f, 0.f, 0.f};
      acc = __builtin_amdgcn_mfma_f32_16x16x32_bf16(aq[0], bk0, acc, 0, 0, 0);
      acc = __builtin_amdgcn_mfma_f32_16x16x32_bf16(aq[1], bk1, acc, 0, 0, 0);
      acc = __builtin_amdgcn_mfma_f32_16x16x32_bf16(aq[2], bk2, acc, 0, 0, 0);
      acc = __builtin_amdgcn_mfma_f32_16x16x32_bf16(aq[3], bk3, acc, 0, 0, 0);
      const int colb = (k0 + l15) * 2;           // C/D: col=lane&15 -> key, row=hi*4+r
#pragma unroll
      for (int r = 0; r < 4; ++r) {
        const int row = hi * 4 + r;
        *(unsigned short*)(smem + row * SC_STRIDE + (colb ^ ((row & 7) << 4))) =
            f2bf(acc[r] * SCALE);
      }
    }
  }
  __syncthreads();

  // ======= phase 2: conv + mask + softmax -> bf16 P in LDS (one wave per row) =======
  const int nrows = (SEQ - g0) < QT_OUT ? (SEQ - g0) : QT_OUT;

  for (int sp = 0; sp < 2; ++sp) {
    const int i = sp * 8 + w;                    // output row i -> q-row g0+i
    const bool act = (i < nrows);
    float p[32];
    float inv = 0.f;
    if (act) {
      const int g = g0 + i;
      const bool vtop = (g > 0), vbot = (g + 1 < SEQ);
#pragma unroll
      for (int jb = 0; jb < 4; ++jb) {
        float m[3][8], Lv[3], Rv[3];
#pragma unroll
        for (int r = 0; r < 3; ++r) {
          const bool v = (r == 1) || ((r == 0) ? vtop : vbot);
          if (v) {
            const int row = i + r;               // score rows i..i+2
            const int rs = row * SC_STRIDE, sw = (row & 7) << 4;
            bf16x8 vv = *(const bf16x8*)(smem + rs + ((jb * 1024 + lane * 16) ^ sw));
#pragma unroll
            for (int c = 0; c < 8; ++c) m[r][c] = bf2f((unsigned short)vv[c]);
            float le = 0.f, re = 0.f;
            if (jb > 0)
              le = bf2f(*(const unsigned short*)(smem + rs + (((jb * 512 - 1) * 2) ^ sw)));
            if (jb < 3)
              re = bf2f(*(const unsigned short*)(smem + rs + (((jb * 512 + 512) * 2) ^ sw)));
            const float lsh = __shfl_up(m[r][7], 1);
            const float rsh = __shfl_down(m[r][0], 1);
            Lv[r] = (lane == 0)  ? le : lsh;
            Rv[r] = (lane == 63) ? re : rsh;
          } else {
#pragma unroll
            for (int c = 0; c < 8; ++c) m[r][c] = 0.f;
            Lv[r] = 0.f; Rv[r] = 0.f;
          }
        }
#pragma unroll
        for (int c = 0; c < 8; ++c) {
          float cv = 0.f;
#pragma unroll
          for (int r = 0; r < 3; ++r) {
            const float lft = (c == 0) ? Lv[r] : m[r][c - 1];
            const float rgt = (c == 7) ? Rv[r] : m[r][c + 1];
            cv += w9[r * 3 + 0] * lft + w9[r * 3 + 1] * m[r][c] + w9[r * 3 + 2] * rgt;
          }
          const float val = m[1][c] + fmaxf(cv + bias, 0.f);
          p[jb * 8 + c] = ((mb >> (jb * 8 + c)) & 1u) ? val : -1e9f;
        }
      }
      float mx = p[0];
#pragma unroll
      for (int k = 1; k < 32; ++k) mx = fmaxf(mx, p[k]);
#pragma unroll
      for (int o = 1; o < 64; o <<= 1) mx = fmaxf(mx, __shfl_xor(mx, o, 64));
      float Z = 0.f;
#pragma unroll
      for (int k = 0; k < 32; ++k) {
        p[k] = __builtin_amdgcn_exp2f((p[k] - mx) * L2E);
        Z += p[k];
      }
#pragma unroll
      for (int o = 1; o < 64; o <<= 1) Z += __shfl_xor(Z, o, 64);
      inv = 1.0f / Z;
    }
    __syncthreads();  // all reads of this sub-phase done before clobbering
    if (act) {
      const int rs = i * SC_STRIDE, sw = (i & 7) << 4;
#pragma unroll
      for (int jb = 0; jb < 4; ++jb) {
        bf16x8 h;
#pragma unroll
        for (int c = 0; c < 8; ++c) h[c] = (short)f2bf(p[jb * 8 + c] * inv);
        *(bf16x8*)(smem + rs + ((jb * 1024 + lane * 16) ^ sw)) = h;
      }
    }
    __syncthreads();
  }

  // ======= phase 3: PV, barrier-free. wave w owns d-cols [16w, 16w+16) =======
  {
    const unsigned short* vp =
        Vt + (size_t)b * DIMD * SEQ + (size_t)(16 * w + l15) * SEQ + hi * 8;
    const int abase = l15 * SC_STRIDE;           // A row = attn row (14,15 garbage->discard)
    const int asw = (l15 & 7) << 4;
    f32x4 acc0 = {0.f, 0.f, 0.f, 0.f}, acc1 = {0.f, 0.f, 0.f, 0.f};
#pragma unroll 4
    for (int kc = 0; kc < 32; ++kc) {
      const int k0 = kc * 64;
      bf16x8 a0 = *(const bf16x8*)(smem + abase + (((k0      ) * 2 + hi * 16) ^ asw));
      bf16x8 b0 = *(const bf16x8*)(vp + k0);
      acc0 = __builtin_amdgcn_mfma_f32_16x16x32_bf16(a0, b0, acc0, 0, 0, 0);
      bf16x8 a1 = *(const bf16x8*)(smem + abase + (((k0 + 32) * 2 + hi * 16) ^ asw));
      bf16x8 b1 = *(const bf16x8*)(vp + k0 + 32);
      acc1 = __builtin_amdgcn_mfma_f32_16x16x32_bf16(a1, b1, acc1, 0, 0, 0);
    }
    const int col = 16 * w + l15;
#pragma unroll
    for (int r = 0; r < 4; ++r) {
      const int row = hi * 4 + r;
      const int g = g0 + row;
      if (row < QT_OUT && g < SEQ)
        ctx[((size_t)(b * SEQ + g)) * DIMD + col] = acc0[r] + acc1[r];
    }
  }

  // ======= phase 4: stream atten f32 to HBM from bf16 P in LDS (dense + nt) =======
  {
    float* attnB = attn + (size_t)b * SEQ * SEQ;
#pragma unroll
    for (int sp = 0; sp < 2; ++sp) {
      const int i = sp * 8 + w;
      if (i < nrows) {
        const int g = g0 + i;
        float* arow = attnB + (size_t)g * SEQ;
        const int rs = i * SC_STRIDE, sw = (i & 7) << 4;
#pragma unroll
        for (int jb = 0; jb < 8; ++jb) {
          uint2 hv = *(const uint2*)(smem + rs + ((jb * 512 + lane * 8) ^ sw));
          f32x4 o;
          o[0] = bf2f((unsigned short)(hv.x & 0xffffu));
          o[1] = bf2f((unsigned short)(hv.x >> 16));
          o[2] = bf2f((unsigned short)(hv.y & 0xffffu));
          o[3] = bf2f((unsigned short)(hv.y >> 16));
          __builtin_nontemporal_store(o, (f32x4*)(arow + jb * 256 + lane * 4));
        }
      }
    }
  }
}

// ---------------- launch ----------------
extern "C" void kernel_launch(void* const* d_in, const int* in_sizes, int n_in,
                              void* d_out, int out_size, void* d_ws, size_t ws_size,
                              hipStream_t stream) {
  const float* Q  = (const float*)d_in[0];
  const float* K  = (const float*)d_in[1];
  const float* V  = (const float*)d_in[2];
  const int* msk  = (const int*)d_in[3];
  const float* cw = (const float*)d_in[4];
  const float* cb = (const float*)d_in[5];
  float* ctx  = (float*)d_out;
  float* attn = ctx + (size_t)B_BATCH * SEQ * DIMD;  // outputs: (context, atten)
  unsigned short* Kb = (unsigned short*)d_ws;        // 8 MiB
  unsigned short* Vt = Kb + (size_t)B_BATCH * SEQ * DIMD;  // 8 MiB

  cvt_bf16<<<2048, 256, 0, stream>>>(K, Kb);
  transpose_v<<<B_BATCH * 64, 256, 0, stream>>>(V, Vt);
  fused_attn<<<B_BATCH * 147, 512, 0, stream>>>(Q, Kb, Vt, msk, cw, cb, ctx, attn);
}

// Round 12
// 366.570 us; speedup vs baseline: 1.1904x; 1.1904x over previous
//
#include <hip/hip_runtime.h>
#include <stdint.h>

// ---------------- problem constants ----------------
#define B_BATCH 16
#define SEQ     2048
#define DIMD    128
#define QT_OUT  14            // output rows per tile
#define SROWS   16            // score rows in LDS (halo +1 each side)
#define SCALE   0.08838834764831845f   // 1/sqrt(128)
#define L2E     1.4426950408889634f

#define SC_STRIDE 4096                 // bytes per score row (2048 bf16)
#define LDS_TOTAL (SROWS * SC_STRIDE)  // 65536 -> 2 blocks/CU

typedef __attribute__((ext_vector_type(8))) short bf16x8;
typedef __attribute__((ext_vector_type(4))) float f32x4;

__device__ __forceinline__ unsigned short f2bf(float f) {
  union { float f; uint32_t u; } v; v.f = f;
  uint32_t u = v.u;
  return (unsigned short)((u + 0x7FFFu + ((u >> 16) & 1u)) >> 16);  // RNE
}
__device__ __forceinline__ float bf2f(unsigned short h) {
  union { uint32_t u; float f; } v; v.u = ((uint32_t)h) << 16;
  return v.f;
}

// ---------------- prepass 1: K fp32 -> bf16 (row-major) ----------------
__global__ __launch_bounds__(256) void cvt_bf16(const float* __restrict__ in,
                                                unsigned short* __restrict__ out) {
  const size_t i = (size_t)blockIdx.x * 256 + threadIdx.x;
  const float4 a = *(const float4*)(in + i * 8);
  const float4 b = *(const float4*)(in + i * 8 + 4);
  uint4 o;
  o.x = (uint32_t)f2bf(a.x) | ((uint32_t)f2bf(a.y) << 16);
  o.y = (uint32_t)f2bf(a.z) | ((uint32_t)f2bf(a.w) << 16);
  o.z = (uint32_t)f2bf(b.x) | ((uint32_t)f2bf(b.y) << 16);
  o.w = (uint32_t)f2bf(b.z) | ((uint32_t)f2bf(b.w) << 16);
  *(uint4*)(out + i * 8) = o;
}

// ---------------- prepass 2: V -> V^T bf16 ([b][d][k]) ----------------
__global__ __launch_bounds__(256) void transpose_v(const float* __restrict__ V,
                                                   unsigned short* __restrict__ Vt) {
  __shared__ float tl[64][65];
  const int b  = blockIdx.x >> 6;
  const int kt = (blockIdx.x & 63) >> 1;
  const int dt = blockIdx.x & 1;
  const int k0 = kt * 64, d0 = dt * 64;
  const int tid = threadIdx.x;
  const int r = tid >> 4, c4 = (tid & 15) * 4;
  const float* Vb = V + (size_t)b * SEQ * DIMD;
#pragma unroll
  for (int ii = 0; ii < 4; ++ii) {
    const int row = ii * 16 + r;
    float4 v = *(const float4*)(Vb + (size_t)(k0 + row) * DIMD + d0 + c4);
    tl[row][c4 + 0] = v.x; tl[row][c4 + 1] = v.y;
    tl[row][c4 + 2] = v.z; tl[row][c4 + 3] = v.w;
  }
  __syncthreads();
  unsigned short* VtB = Vt + (size_t)b * DIMD * SEQ;
#pragma unroll
  for (int ii = 0; ii < 4; ++ii) {
    const int drow = ii * 16 + r;
    ushort4 o;
    o.x = f2bf(tl[c4 + 0][drow]); o.y = f2bf(tl[c4 + 1][drow]);
    o.z = f2bf(tl[c4 + 2][drow]); o.w = f2bf(tl[c4 + 3][drow]);
    *(ushort4*)(VtB + (size_t)(d0 + drow) * SEQ + k0 + c4) = o;
  }
}

// ---------------- fused: QK^T -> conv -> softmax -> (PV, atten out) ----------------
// R11 body (traffic-ideal: WRITE==output size, no spill) + (512,4) launch bounds
// (R7-proven 2 blocks/CU co-residency). VGPR cap 128 >= the ~76 naturally used.
__global__ __launch_bounds__(512, 4) void fused_attn(
    const float* __restrict__ Q, const unsigned short* __restrict__ Kb,
    const unsigned short* __restrict__ Vt, const int* __restrict__ msk,
    const float* __restrict__ cw, const float* __restrict__ cbv,
    float* __restrict__ ctx, float* __restrict__ attn) {
  __shared__ __align__(16) char smem[LDS_TOTAL];

  const int bid = blockIdx.x;
  // batch<->XCD affinity: b%8 == bid%8 -> 2 batches per XCD L2
  const int b  = bid & 15;
  const int t  = bid >> 4;
  const int g0 = t * QT_OUT;
  const int tid = threadIdx.x;
  const int w = tid >> 6, lane = tid & 63, l15 = lane & 15, hi = lane >> 4;

  float w9[9];
#pragma unroll
  for (int i = 0; i < 9; ++i) w9[i] = cw[b * 9 + i];
  const float bias = cbv[b];

  // per-lane column mask bits: col = jb*512 + lane*8 + c  ->  bit jb*8+c
  uint32_t mb = 0;
  {
    const int* mp = msk + b * SEQ;
#pragma unroll
    for (int jb = 0; jb < 4; ++jb) {
      int4 a = *(const int4*)(mp + jb * 512 + lane * 8);
      int4 bq = *(const int4*)(mp + jb * 512 + lane * 8 + 4);
      mb |= (a.x  != 0 ? 1u : 0u) << (jb * 8 + 0);
      mb |= (a.y  != 0 ? 1u : 0u) << (jb * 8 + 1);
      mb |= (a.z  != 0 ? 1u : 0u) << (jb * 8 + 2);
      mb |= (a.w  != 0 ? 1u : 0u) << (jb * 8 + 3);
      mb |= (bq.x != 0 ? 1u : 0u) << (jb * 8 + 4);
      mb |= (bq.y != 0 ? 1u : 0u) << (jb * 8 + 5);
      mb |= (bq.z != 0 ? 1u : 0u) << (jb * 8 + 6);
      mb |= (bq.w != 0 ? 1u : 0u) << (jb * 8 + 7);
    }
  }

  // ---- Q fragments (A operand): score row l15 = q-row g0-1+l15 (clamped; gated at conv) ----
  bf16x8 aq[4];
  {
    int grow = g0 - 1 + l15;
    grow = grow < 0 ? 0 : (grow > SEQ - 1 ? SEQ - 1 : grow);
    const float* qp = Q + ((size_t)(b * SEQ + grow)) * DIMD + hi * 8;
#pragma unroll
    for (int ks = 0; ks < 4; ++ks) {
      float4 x = *(const float4*)(qp + ks * 32);
      float4 y = *(const float4*)(qp + ks * 32 + 4);
      bf16x8 f;
      f[0] = (short)f2bf(x.x); f[1] = (short)f2bf(x.y);
      f[2] = (short)f2bf(x.z); f[3] = (short)f2bf(x.w);
      f[4] = (short)f2bf(y.x); f[5] = (short)f2bf(y.y);
      f[6] = (short)f2bf(y.z); f[7] = (short)f2bf(y.w);
      aq[ks] = f;
    }
  }

  // ======= phase 1: QK^T, barrier-free. wave w owns keys [w*256, w*256+256) =======
  {
    const unsigned short* KbB = Kb + (size_t)b * SEQ * DIMD;
    const int k0w = w * 256;
#pragma unroll 4
    for (int kc = 0; kc < 16; ++kc) {
      const int k0 = k0w + kc * 16;
      const unsigned short* kp = KbB + (size_t)(k0 + l15) * DIMD + hi * 8;
      bf16x8 bk0 = *(const bf16x8*)(kp);
      bf16x8 bk1 = *(const bf16x8*)(kp + 32);
      bf16x8 bk2 = *(const bf16x8*)(kp + 64);
      bf16x8 bk3 = *(const bf16x8*)(kp + 96);
      f32x4 acc = {0.f, 0.f, 0.f, 0.f};
      acc = __builtin_amdgcn_mfma_f32_16x16x32_bf16(aq[0], bk0, acc, 0, 0, 0);
      acc = __builtin_amdgcn_mfma_f32_16x16x32_bf16(aq[1], bk1, acc, 0, 0, 0);
      acc = __builtin_amdgcn_mfma_f32_16x16x32_bf16(aq[2], bk2, acc, 0, 0, 0);
      acc = __builtin_amdgcn_mfma_f32_16x16x32_bf16(aq[3], bk3, acc, 0, 0, 0);
      const int colb = (k0 + l15) * 2;           // C/D: col=lane&15 -> key, row=hi*4+r
#pragma unroll
      for (int r = 0; r < 4; ++r) {
        const int row = hi * 4 + r;
        *(unsigned short*)(smem + row * SC_STRIDE + (colb ^ ((row & 7) << 4))) =
            f2bf(acc[r] * SCALE);
      }
    }
  }
  __syncthreads();

  // ======= phase 2: conv + mask + softmax -> bf16 P in LDS (one wave per row) =======
  const int nrows = (SEQ - g0) < QT_OUT ? (SEQ - g0) : QT_OUT;

  for (int sp = 0; sp < 2; ++sp) {
    const int i = sp * 8 + w;                    // output row i -> q-row g0+i
    const bool act = (i < nrows);
    float p[32];
    float inv = 0.f;
    if (act) {
      const int g = g0 + i;
      const bool vtop = (g > 0), vbot = (g + 1 < SEQ);
#pragma unroll
      for (int jb = 0; jb < 4; ++jb) {
        float m[3][8], Lv[3], Rv[3];
#pragma unroll
        for (int r = 0; r < 3; ++r) {
          const bool v = (r == 1) || ((r == 0) ? vtop : vbot);
          if (v) {
            const int row = i + r;               // score rows i..i+2
            const int rs = row * SC_STRIDE, sw = (row & 7) << 4;
            bf16x8 vv = *(const bf16x8*)(smem + rs + ((jb * 1024 + lane * 16) ^ sw));
#pragma unroll
            for (int c = 0; c < 8; ++c) m[r][c] = bf2f((unsigned short)vv[c]);
            float le = 0.f, re = 0.f;
            if (jb > 0)
              le = bf2f(*(const unsigned short*)(smem + rs + (((jb * 512 - 1) * 2) ^ sw)));
            if (jb < 3)
              re = bf2f(*(const unsigned short*)(smem + rs + (((jb * 512 + 512) * 2) ^ sw)));
            const float lsh = __shfl_up(m[r][7], 1);
            const float rsh = __shfl_down(m[r][0], 1);
            Lv[r] = (lane == 0)  ? le : lsh;
            Rv[r] = (lane == 63) ? re : rsh;
          } else {
#pragma unroll
            for (int c = 0; c < 8; ++c) m[r][c] = 0.f;
            Lv[r] = 0.f; Rv[r] = 0.f;
          }
        }
#pragma unroll
        for (int c = 0; c < 8; ++c) {
          float cv = 0.f;
#pragma unroll
          for (int r = 0; r < 3; ++r) {
            const float lft = (c == 0) ? Lv[r] : m[r][c - 1];
            const float rgt = (c == 7) ? Rv[r] : m[r][c + 1];
            cv += w9[r * 3 + 0] * lft + w9[r * 3 + 1] * m[r][c] + w9[r * 3 + 2] * rgt;
          }
          const float val = m[1][c] + fmaxf(cv + bias, 0.f);
          p[jb * 8 + c] = ((mb >> (jb * 8 + c)) & 1u) ? val : -1e9f;
        }
      }
      float mx = p[0];
#pragma unroll
      for (int k = 1; k < 32; ++k) mx = fmaxf(mx, p[k]);
#pragma unroll
      for (int o = 1; o < 64; o <<= 1) mx = fmaxf(mx, __shfl_xor(mx, o, 64));
      float Z = 0.f;
#pragma unroll
      for (int k = 0; k < 32; ++k) {
        p[k] = __builtin_amdgcn_exp2f((p[k] - mx) * L2E);
        Z += p[k];
      }
#pragma unroll
      for (int o = 1; o < 64; o <<= 1) Z += __shfl_xor(Z, o, 64);
      inv = 1.0f / Z;
    }
    __syncthreads();  // all reads of this sub-phase done before clobbering
    if (act) {
      const int rs = i * SC_STRIDE, sw = (i & 7) << 4;
#pragma unroll
      for (int jb = 0; jb < 4; ++jb) {
        bf16x8 h;
#pragma unroll
        for (int c = 0; c < 8; ++c) h[c] = (short)f2bf(p[jb * 8 + c] * inv);
        *(bf16x8*)(smem + rs + ((jb * 1024 + lane * 16) ^ sw)) = h;
      }
    }
    __syncthreads();
  }

  // ======= phase 3: PV, barrier-free. wave w owns d-cols [16w, 16w+16) =======
  {
    const unsigned short* vp =
        Vt + (size_t)b * DIMD * SEQ + (size_t)(16 * w + l15) * SEQ + hi * 8;
    const int abase = l15 * SC_STRIDE;           // A row = attn row (14,15 garbage->discard)
    const int asw = (l15 & 7) << 4;
    f32x4 acc0 = {0.f, 0.f, 0.f, 0.f}, acc1 = {0.f, 0.f, 0.f, 0.f};
#pragma unroll 4
    for (int kc = 0; kc < 32; ++kc) {
      const int k0 = kc * 64;
      bf16x8 a0 = *(const bf16x8*)(smem + abase + (((k0      ) * 2 + hi * 16) ^ asw));
      bf16x8 b0 = *(const bf16x8*)(vp + k0);
      acc0 = __builtin_amdgcn_mfma_f32_16x16x32_bf16(a0, b0, acc0, 0, 0, 0);
      bf16x8 a1 = *(const bf16x8*)(smem + abase + (((k0 + 32) * 2 + hi * 16) ^ asw));
      bf16x8 b1 = *(const bf16x8*)(vp + k0 + 32);
      acc1 = __builtin_amdgcn_mfma_f32_16x16x32_bf16(a1, b1, acc1, 0, 0, 0);
    }
    const int col = 16 * w + l15;
#pragma unroll
    for (int r = 0; r < 4; ++r) {
      const int row = hi * 4 + r;
      const int g = g0 + row;
      if (row < QT_OUT && g < SEQ)
        ctx[((size_t)(b * SEQ + g)) * DIMD + col] = acc0[r] + acc1[r];
    }
  }

  // ======= phase 4: stream atten f32 to HBM from bf16 P in LDS (dense + nt) =======
  {
    float* attnB = attn + (size_t)b * SEQ * SEQ;
#pragma unroll
    for (int sp = 0; sp < 2; ++sp) {
      const int i = sp * 8 + w;
      if (i < nrows) {
        const int g = g0 + i;
        float* arow = attnB + (size_t)g * SEQ;
        const int rs = i * SC_STRIDE, sw = (i & 7) << 4;
#pragma unroll
        for (int jb = 0; jb < 8; ++jb) {
          uint2 hv = *(const uint2*)(smem + rs + ((jb * 512 + lane * 8) ^ sw));
          f32x4 o;
          o[0] = bf2f((unsigned short)(hv.x & 0xffffu));
          o[1] = bf2f((unsigned short)(hv.x >> 16));
          o[2] = bf2f((unsigned short)(hv.y & 0xffffu));
          o[3] = bf2f((unsigned short)(hv.y >> 16));
          __builtin_nontemporal_store(o, (f32x4*)(arow + jb * 256 + lane * 4));
        }
      }
    }
  }
}

// ---------------- launch ----------------
extern "C" void kernel_launch(void* const* d_in, const int* in_sizes, int n_in,
                              void* d_out, int out_size, void* d_ws, size_t ws_size,
                              hipStream_t stream) {
  const float* Q  = (const float*)d_in[0];
  const float* K  = (const float*)d_in[1];
  const float* V  = (const float*)d_in[2];
  const int* msk  = (const int*)d_in[3];
  const float* cw = (const float*)d_in[4];
  const float* cb = (const float*)d_in[5];
  float* ctx  = (float*)d_out;
  float* attn = ctx + (size_t)B_BATCH * SEQ * DIMD;  // outputs: (context, atten)
  unsigned short* Kb = (unsigned short*)d_ws;        // 8 MiB
  unsigned short* Vt = Kb + (size_t)B_BATCH * SEQ * DIMD;  // 8 MiB

  cvt_bf16<<<2048, 256, 0, stream>>>(K, Kb);
  transpose_v<<<B_BATCH * 64, 256, 0, stream>>>(V, Vt);
  fused_attn<<<B_BATCH * 147, 512, 0, stream>>>(Q, Kb, Vt, msk, cw, cb, ctx, attn);
}